// Round 1
// baseline (320.128 us; speedup 1.0000x reference)
//
#include <hip/hip_runtime.h>

#define KF   16
#define DIM  64
#define WPB  4
#define BLOCK (WPB * 64)

__device__ __forceinline__ float fsig(float x) {
    return __builtin_amdgcn_rcpf(1.0f + __expf(-x));
}
__device__ __forceinline__ float ftanh(float x) {
    float e = __expf(2.0f * x);
    return 1.0f - 2.0f * __builtin_amdgcn_rcpf(e + 1.0f);
}

__global__ __launch_bounds__(BLOCK) void kgcn_kernel(
    const int* __restrict__ u, const int* __restrict__ v,
    const int* __restrict__ adj_ent, const int* __restrict__ adj_rel,
    const float* __restrict__ usr_emb, const float* __restrict__ rel_emb,
    const float* __restrict__ ent_emb, const float* __restrict__ W,
    const float* __restrict__ bias, float* __restrict__ out, int B)
{
    __shared__ float W_l[DIM * DIM];          // 16 KB, W[d][j] row-major
    __shared__ float b_l[DIM];
    __shared__ float relT[DIM][33];           // rel_emb transposed, padded (+1 breaks conflicts)
    __shared__ float urs_l[WPB][32];          // user . rel_emb[r], all 32 relations
    __shared__ int   e1l[WPB][KF];
    __shared__ float at1[WPB][KF];            // hop-0 scores -> attn (reused by layer 2)
    __shared__ int   e2l[WPB][KF * KF];
    __shared__ float at2[WPB][KF * KF];       // hop-1 scores -> attn
    __shared__ __align__(16) float xl[WPB][DIM];

    const int tid  = threadIdx.x;
    const int lane = tid & 63;
    const int w    = tid >> 6;

    // ---- block-level staging ----
    for (int i = tid; i < DIM * DIM; i += BLOCK) W_l[i] = W[i];
    if (tid < DIM) b_l[tid] = bias[tid];
    for (int i = tid; i < 32 * DIM; i += BLOCK) {
        relT[i & 63][i >> 6] = rel_emb[i];    // relT[d][r]
    }
    __syncthreads();

    const int b = blockIdx.x * WPB + w;
    if (b >= B) return;

    // ---- user vector: lane d holds user[d] ----
    const float user = usr_emb[(size_t)u[b] * DIM + lane];
    xl[w][lane] = user;

    // ---- urs[r] = user . rel_emb[r] for all 32 relations ----
    {
        const int r = lane & 31, h = lane >> 5;
        float s = 0.0f;
        #pragma unroll
        for (int dd = 0; dd < 32; ++dd) {
            const int d = h * 32 + dd;
            s += xl[w][d] * relT[d][r];       // 2-way bank alias only (free)
        }
        s += __shfl_xor(s, 32);               // combine the two halves
        if (lane < 32) urs_l[w][lane] = s;
    }

    // ---- adjacency expansion + raw scores ----
    const int e0 = v[b];
    if (lane < KF) {
        const int e1 = adj_ent[e0 * KF + lane];
        const int r1 = adj_rel[e0 * KF + lane];
        e1l[w][lane] = e1;
        at1[w][lane] = urs_l[w][r1];
    }
    #pragma unroll
    for (int it = 0; it < 4; ++it) {
        const int i = it * 64 + lane;         // 0..255
        const int m = i >> 4, k = i & 15;
        const int em = e1l[w][m];
        e2l[w][i] = adj_ent[em * KF + k];
        at2[w][i] = urs_l[w][adj_rel[em * KF + k]];
    }

    // ---- softmax over each group of 16 (contiguous lanes) ----
    #pragma unroll
    for (int it = 0; it < 4; ++it) {
        float s  = at2[w][it * 64 + lane];
        float mx = s;
        mx = fmaxf(mx, __shfl_xor(mx, 1));
        mx = fmaxf(mx, __shfl_xor(mx, 2));
        mx = fmaxf(mx, __shfl_xor(mx, 4));
        mx = fmaxf(mx, __shfl_xor(mx, 8));
        float e = __expf(s - mx);
        float sum = e;
        sum += __shfl_xor(sum, 1);
        sum += __shfl_xor(sum, 2);
        sum += __shfl_xor(sum, 4);
        sum += __shfl_xor(sum, 8);
        at2[w][it * 64 + lane] = e * __builtin_amdgcn_rcpf(sum);
    }
    {
        float s  = at1[w][lane & 15];         // every 16-lane group computes redundantly
        float mx = s;
        mx = fmaxf(mx, __shfl_xor(mx, 1));
        mx = fmaxf(mx, __shfl_xor(mx, 2));
        mx = fmaxf(mx, __shfl_xor(mx, 4));
        mx = fmaxf(mx, __shfl_xor(mx, 8));
        float e = __expf(s - mx);
        float sum = e;
        sum += __shfl_xor(sum, 1);
        sum += __shfl_xor(sum, 2);
        sum += __shfl_xor(sum, 4);
        sum += __shfl_xor(sum, 8);
        if (lane < KF) at1[w][lane] = e * __builtin_amdgcn_rcpf(sum);
    }

    // ---- matvec: out[j] = bias[j] + sum_d x[d] * W[d][j]  (lane = j) ----
    auto matvec = [&](float x) -> float {
        xl[w][lane] = x;
        float acc = b_l[lane];
        #pragma unroll
        for (int d = 0; d < DIM; d += 4) {
            const float4 xv = *(const float4*)&xl[w][d];  // broadcast read
            acc = fmaf(xv.x, W_l[(d + 0) * DIM + lane], acc);
            acc = fmaf(xv.y, W_l[(d + 1) * DIM + lane], acc);
            acc = fmaf(xv.z, W_l[(d + 2) * DIM + lane], acc);
            acc = fmaf(xv.w, W_l[(d + 3) * DIM + lane], acc);
        }
        return acc;
    };

    // ---- layer-1 hop-1 (16 nodes) fused with layer-2 aggregation ----
    float agg2 = 0.0f;                        // sum_m attn1[m] * h1[m][lane]
    #pragma unroll 1
    for (int m = 0; m < KF; ++m) {
        float agg = 0.0f;
        #pragma unroll
        for (int k = 0; k < KF; ++k) {
            const int e = __builtin_amdgcn_readfirstlane(e2l[w][m * KF + k]);
            agg = fmaf(at2[w][m * KF + k], ent_emb[(size_t)e * DIM + lane], agg);
        }
        const int es = __builtin_amdgcn_readfirstlane(e1l[w][m]);
        const float x = ent_emb[(size_t)es * DIM + lane] + agg;
        const float h1m = fsig(matvec(x));
        agg2 = fmaf(at1[w][m], h1m, agg2);
    }

    // ---- layer-1 hop-0 ----
    float agg0 = 0.0f;
    #pragma unroll
    for (int k = 0; k < KF; ++k) {
        const int e = __builtin_amdgcn_readfirstlane(e1l[w][k]);
        agg0 = fmaf(at1[w][k], ent_emb[(size_t)e * DIM + lane], agg0);
    }
    const float x0 = ent_emb[(size_t)e0 * DIM + lane] + agg0;
    const float h0 = fsig(matvec(x0));

    // ---- layer 2 (attn identical to at1: same user, same relations) ----
    const float x2   = h0 + agg2;
    const float item = ftanh(matvec(x2));

    // ---- final dot + sigmoid ----
    float p = user * item;
    p += __shfl_xor(p, 1);
    p += __shfl_xor(p, 2);
    p += __shfl_xor(p, 4);
    p += __shfl_xor(p, 8);
    p += __shfl_xor(p, 16);
    p += __shfl_xor(p, 32);
    if (lane == 0) out[b] = fsig(p);
}

extern "C" void kernel_launch(void* const* d_in, const int* in_sizes, int n_in,
                              void* d_out, int out_size, void* d_ws, size_t ws_size,
                              hipStream_t stream) {
    const int*   u       = (const int*)d_in[0];
    const int*   v       = (const int*)d_in[1];
    const int*   adj_ent = (const int*)d_in[2];
    const int*   adj_rel = (const int*)d_in[3];
    const float* usr_emb = (const float*)d_in[4];
    const float* rel_emb = (const float*)d_in[5];
    const float* ent_emb = (const float*)d_in[6];
    const float* W       = (const float*)d_in[7];
    const float* bias    = (const float*)d_in[8];
    float* out = (float*)d_out;

    const int B = in_sizes[0];
    const int grid = (B + WPB - 1) / WPB;
    kgcn_kernel<<<grid, BLOCK, 0, stream>>>(u, v, adj_ent, adj_rel,
                                            usr_emb, rel_emb, ent_emb,
                                            W, bias, out, B);
}